// Round 17
// baseline (38.285 us; speedup 1.0000x reference)
//
#include <hip/hip_runtime.h>

constexpr int KWIN = 100;
constexpr int HK   = 50;
constexpr int TSUB = 64;    // frames per chunk (4 groups of 16)
constexpr int MB   = 4;     // outputs per batch, A/B pipelined
constexpr int PB   = 25;    // prime batch

typedef float f32x4 __attribute__((ext_vector_type(4)));

__device__ __forceinline__ int ridx(int t) {
    constexpr int T = 16384;
    t = (t < 0) ? -t : t;
    return (t >= T) ? (2 * T - 2 - t) : t;
}

__global__ __launch_bounds__(256, 2) void man_kernel(
    const float* __restrict__ x, float* __restrict__ out)
{
    constexpr int T = 16384, D = 128;
    __shared__ float sbuf[2][2][16 * 128];        // 32 KB: [buf][w][j*128+d]

    const int i   = blockIdx.x;                   // 0..1023
    const int bb  = (i & 7) * 128 + (i >> 3);     // XCD (i&7) owns batch b
    const int b   = bb >> 7;                      // 0..7
    const int seg = bb & 127;                     // pair of adjacent chunks
    const int w   = threadIdx.x >> 7;             // chunk within pair
    const int d   = threadIdx.x & 127;            // column
    const int t0  = (seg * 2 + w) * TSUB;

    const float* __restrict__ xb = x + (size_t)b * T * D + d;
    float* __restrict__ og = out + (size_t)b * T * D + (size_t)t0 * D;

    const float invK = 1.0f / 100.0f, invKm1 = 1.0f / 99.0f, fK = 100.0f;

    float ring[HK];                               // frames t0+k.., static idx
    float sx = 0.f, sq = 0.f;

    if (seg == 0 || seg == 127) {
        // ---- block-uniform boundary path: reflect, scalar stores, NO barriers
        #pragma unroll
        for (int s = 0; s < HK; ++s) {
            float v = xb[(size_t)ridx(t0 - HK + s) * D];
            sx += v; sq = fmaf(v, v, sq);
        }
        #pragma unroll
        for (int s = 0; s < HK; ++s) {
            float v = xb[(size_t)ridx(t0 + s) * D];
            ring[s] = v; sx += v; sq = fmaf(v, v, sq);
        }
        #pragma unroll
        for (int k = 0; k < TSUB; ++k) {
            float in = xb[(size_t)ridx(t0 + k + HK) * D];
            float o  = xb[(size_t)ridx(t0 + k - HK) * D];
            float c  = ring[k % HK];
            float m  = sx * invK;
            float va = fmaxf((sq - fK * m * m) * invKm1, 1e-24f);
            float rs = __builtin_amdgcn_rsqf(va);
            og[(size_t)k * D + d] = (c - m) * rs;
            sx += in - o; sq += in * in - o * o;
            ring[k % HK] = in;
        }
        return;
    }

    // ---- interior: linear addressing ----
    {   // prime: frames [t0-50, t0+49]; low half sums-only, high half -> ring
        float la[PB], lb_[PB];
        #pragma unroll
        for (int j = 0; j < PB; ++j) la[j]  = xb[(size_t)(t0 - HK + j) * D];
        #pragma unroll
        for (int j = 0; j < PB; ++j) lb_[j] = xb[(size_t)(t0 - PB + j) * D];
        #pragma unroll
        for (int j = 0; j < PB; ++j) { sx += la[j]; sq = fmaf(la[j], la[j], sq); }
        #pragma unroll
        for (int j = 0; j < PB; ++j) la[j] = xb[(size_t)(t0 + j) * D];
        #pragma unroll
        for (int j = 0; j < PB; ++j) { sx += lb_[j]; sq = fmaf(lb_[j], lb_[j], sq); }
        #pragma unroll
        for (int j = 0; j < PB; ++j) lb_[j] = xb[(size_t)(t0 + PB + j) * D];
        #pragma unroll
        for (int j = 0; j < PB; ++j) { ring[j] = la[j]; sx += la[j]; sq = fmaf(la[j], la[j], sq); }
        #pragma unroll
        for (int j = 0; j < PB; ++j) { ring[PB + j] = lb_[j]; sx += lb_[j]; sq = fmaf(lb_[j], lb_[j], sq); }
    }

    // ---- main: 16 batches of 4; outputs staged in LDS, flushed as f32x4 ----
    float inA[MB], oA[MB], inB[MB], oB[MB];

#define LOADB(IN, OU, KB)                                                     \
    {                                                                         \
        _Pragma("unroll")                                                     \
        for (int j = 0; j < MB; ++j) {                                        \
            IN[j] = xb[(size_t)(t0 + (KB) * MB + j + HK) * D];                \
            OU[j] = xb[(size_t)(t0 + (KB) * MB + j - HK) * D];                \
        }                                                                     \
    }

#define COMPUTEB(IN, OU, KB)                                                  \
    {                                                                         \
        _Pragma("unroll")                                                     \
        for (int j = 0; j < MB; ++j) {                                        \
            const int k = (KB) * MB + j;                                      \
            const float c  = ring[k % HK];                                    \
            const float m  = sx * invK;                                       \
            const float va = fmaxf((sq - fK * m * m) * invKm1, 1e-24f);       \
            const float rs = __builtin_amdgcn_rsqf(va);                       \
            sbuf[((KB) / 4) & 1][w][(k % 16) * 128 + d] = (c - m) * rs;       \
            sx += IN[j] - OU[j];                                              \
            sq += IN[j] * IN[j] - OU[j] * OU[j];                              \
            ring[k % HK] = IN[j];                                             \
        }                                                                     \
    }

    // flush group G (16 frames, 8 KB per w-half) as 4 coalesced f32x4 stores:
    // lanes of a wave cover 1 KB contiguous output -> fill-kernel store pattern
#define FLUSH(G)                                                              \
    {                                                                         \
        asm volatile("s_waitcnt lgkmcnt(0)\n\ts_barrier" ::: "memory");       \
        const float* ls_ = &sbuf[(G) & 1][w][0];                              \
        _Pragma("unroll")                                                     \
        for (int p = 0; p < 4; ++p) {                                         \
            f32x4 v = *(const f32x4*)(ls_ + p * 512 + d * 4);                 \
            *(f32x4*)(&og[(size_t)((G) * 16 + p * 4 + (d >> 5)) * D           \
                          + (d & 31) * 4]) = v;                               \
        }                                                                     \
    }

    LOADB(inA, oA, 0); LOADB(inB, oB, 1);
    COMPUTEB(inA, oA, 0);  LOADB(inA, oA, 2);
    COMPUTEB(inB, oB, 1);  LOADB(inB, oB, 3);
    COMPUTEB(inA, oA, 2);  LOADB(inA, oA, 4);
    COMPUTEB(inB, oB, 3);  LOADB(inB, oB, 5);  FLUSH(0);
    COMPUTEB(inA, oA, 4);  LOADB(inA, oA, 6);
    COMPUTEB(inB, oB, 5);  LOADB(inB, oB, 7);
    COMPUTEB(inA, oA, 6);  LOADB(inA, oA, 8);
    COMPUTEB(inB, oB, 7);  LOADB(inB, oB, 9);  FLUSH(1);
    COMPUTEB(inA, oA, 8);  LOADB(inA, oA, 10);
    COMPUTEB(inB, oB, 9);  LOADB(inB, oB, 11);
    COMPUTEB(inA, oA, 10); LOADB(inA, oA, 12);
    COMPUTEB(inB, oB, 11); LOADB(inB, oB, 13); FLUSH(2);
    COMPUTEB(inA, oA, 12); LOADB(inA, oA, 14);
    COMPUTEB(inB, oB, 13); LOADB(inB, oB, 15);
    COMPUTEB(inA, oA, 14);
    COMPUTEB(inB, oB, 15);
    FLUSH(3);

#undef LOADB
#undef COMPUTEB
#undef FLUSH
}

extern "C" void kernel_launch(void* const* d_in, const int* in_sizes, int n_in,
                              void* d_out, int out_size, void* d_ws, size_t ws_size,
                              hipStream_t stream) {
    (void)in_sizes; (void)n_in; (void)d_ws; (void)ws_size; (void)out_size;
    const float* x = (const float*)d_in[0];
    float* out = (float*)d_out;
    // 8 b * 256 chunks * 128 d = 262144 threads = 1024 blocks * 256
    man_kernel<<<dim3(1024), dim3(256), 0, stream>>>(x, out);
}